// Round 6
// baseline (819.140 us; speedup 1.0000x reference)
//
#include <hip/hip_runtime.h>
#include <math.h>

#define SEQ 2516
#define CDIM 128

__device__ __forceinline__ float gelu_exact(float x) {
    return x * 0.5f * (1.0f + erff(x * 0.7071067811865475f));
}
__device__ __forceinline__ float fexp2(float x) { return __builtin_amdgcn_exp2f(x); }

// ---------------- concat + LN1(layer0): one wave per row ------------------------
__global__ __launch_bounds__(64) void concat_ln_kernel(
    const float* __restrict__ td, const float* __restrict__ sup,
    const float* __restrict__ g, const float* __restrict__ b,
    float* __restrict__ X, float* __restrict__ H) {
    const int row = blockIdx.x;
    const int t = threadIdx.x;
    float x0, x1;
    if (row < 16) {
        x0 = td[row * 128 + t];
        x1 = td[row * 128 + 64 + t];
    } else {
        int r = row - 16;
        int n = r / 100, p = r - n * 100;
        x0 = sup[n * 12800 + t * 100 + p];
        x1 = sup[n * 12800 + (t + 64) * 100 + p];
    }
    X[row * 128 + t] = x0;
    X[row * 128 + 64 + t] = x1;
    float s = x0 + x1;
    for (int off = 32; off > 0; off >>= 1) s += __shfl_down(s, off);
    float mean = __shfl(s, 0) * (1.f / 128.f);
    float d0 = x0 - mean, d1 = x1 - mean;
    float v = d0 * d0 + d1 * d1;
    for (int off = 32; off > 0; off >>= 1) v += __shfl_down(v, off);
    float var = __shfl(v, 0) * (1.f / 128.f);
    float rstd = rsqrtf(var + 1e-5f);
    H[row * 128 + t]      = d0 * rstd * g[t] + b[t];
    H[row * 128 + 64 + t] = d1 * rstd * g[t + 64] + b[t + 64];
}

// ---------------- skinny GEMM: 8 M-rows x N cols per block ----------------------
template<int N, int RPT, int ACT, bool RES>
__global__ __launch_bounds__(N * 8 / RPT) void sgemm_kernel(
    const float* __restrict__ A, const float* __restrict__ W,
    const float* __restrict__ bias, const float* __restrict__ R,
    float* __restrict__ C, int M, int K) {
    const int t = threadIdx.x;
    const int c = t % N;
    const int grp = __builtin_amdgcn_readfirstlane(t / N);
    const int r0 = blockIdx.x * 8 + grp * RPT;
    float acc[RPT];
    #pragma unroll
    for (int i = 0; i < RPT; ++i) acc[i] = 0.f;
    #pragma unroll 4
    for (int k0 = 0; k0 < K; k0 += 4) {
        float w0 = W[(size_t)(k0 + 0) * N + c];
        float w1 = W[(size_t)(k0 + 1) * N + c];
        float w2 = W[(size_t)(k0 + 2) * N + c];
        float w3 = W[(size_t)(k0 + 3) * N + c];
        #pragma unroll
        for (int i = 0; i < RPT; ++i) {
            float4 a4 = *(const float4*)&A[(size_t)(r0 + i) * K + k0];
            acc[i] = fmaf(a4.x, w0, acc[i]);
            acc[i] = fmaf(a4.y, w1, acc[i]);
            acc[i] = fmaf(a4.z, w2, acc[i]);
            acc[i] = fmaf(a4.w, w3, acc[i]);
        }
    }
    float bv = bias[c];
    #pragma unroll
    for (int i = 0; i < RPT; ++i) {
        int row = r0 + i;
        if (row < M) {
            float v = acc[i] + bv;
            if (ACT == 1) v = gelu_exact(v);
            if (RES) v += R[(size_t)row * N + c];
            C[(size_t)row * N + c] = v;
        }
    }
}

// ------- skinny GEMM N=128 + residual + row-LN epilogue (writes C and H) --------
// 512 thr, c = t&127, grp = t>>7 (wave-uniform), rows r0+grp*2+{0,1}.
// After stores, the 8 rows sit in LDS; wave w row-LNs row w into H.
__global__ __launch_bounds__(512) void sgemm_ln_kernel(
    const float* __restrict__ A, const float* __restrict__ W,
    const float* __restrict__ bias, const float* __restrict__ R,
    float* __restrict__ C, float* __restrict__ H,
    const float* __restrict__ g, const float* __restrict__ bb, int M, int K) {
    __shared__ float ln[8][130];
    const int t = threadIdx.x;
    const int c = t & 127;
    const int grp = __builtin_amdgcn_readfirstlane(t >> 7);
    const int r0 = blockIdx.x * 8 + grp * 2;
    float acc0 = 0.f, acc1 = 0.f;
    #pragma unroll 4
    for (int k0 = 0; k0 < K; k0 += 4) {
        float w0 = W[(size_t)(k0 + 0) * 128 + c];
        float w1 = W[(size_t)(k0 + 1) * 128 + c];
        float w2 = W[(size_t)(k0 + 2) * 128 + c];
        float w3 = W[(size_t)(k0 + 3) * 128 + c];
        float4 a0 = *(const float4*)&A[(size_t)(r0 + 0) * K + k0];
        float4 a1 = *(const float4*)&A[(size_t)(r0 + 1) * K + k0];
        acc0 = fmaf(a0.x, w0, acc0); acc0 = fmaf(a0.y, w1, acc0);
        acc0 = fmaf(a0.z, w2, acc0); acc0 = fmaf(a0.w, w3, acc0);
        acc1 = fmaf(a1.x, w0, acc1); acc1 = fmaf(a1.y, w1, acc1);
        acc1 = fmaf(a1.z, w2, acc1); acc1 = fmaf(a1.w, w3, acc1);
    }
    float bv = bias[c];
    float v0 = acc0 + bv + R[(size_t)(r0 + 0) * 128 + c];
    float v1 = acc1 + bv + R[(size_t)(r0 + 1) * 128 + c];
    ln[grp * 2 + 0][c] = v0;
    ln[grp * 2 + 1][c] = v1;
    if (r0 + 0 < M) C[(size_t)(r0 + 0) * 128 + c] = v0;
    if (r0 + 1 < M) C[(size_t)(r0 + 1) * 128 + c] = v1;
    __syncthreads();
    const int wv = t >> 6, l = t & 63;
    float x0 = ln[wv][l], x1 = ln[wv][l + 64];
    float s = x0 + x1;
    for (int off = 32; off > 0; off >>= 1) s += __shfl_down(s, off);
    float mean = __shfl(s, 0) * (1.f / 128.f);
    float d0 = x0 - mean, d1 = x1 - mean;
    float vv = d0 * d0 + d1 * d1;
    for (int off = 32; off > 0; off >>= 1) vv += __shfl_down(vv, off);
    float var = __shfl(vv, 0) * (1.f / 128.f);
    float rstd = rsqrtf(var + 1e-5f);
    const int hrow = blockIdx.x * 8 + wv;
    H[(size_t)hrow * 128 + l]      = d0 * rstd * g[l] + bb[l];
    H[(size_t)hrow * 128 + 64 + l] = d1 * rstd * g[l + 64] + bb[l + 64];
}

// ---------------- attention v6: fp32, QB=4, Q-tile 16, swizzled LDS -------------
// grid (158, 8 heads), block 256 (4 waves). qg = t&3 -> 4 query rows; chunk=t>>2
// (64 chunks x 4 keys per 256-key tile). 42 KB LDS -> 3 blocks/CU resident.
__device__ __forceinline__ int kvswz(int r) { return r * 20 + ((r >> 4) & 3) * 8; }

__global__ __launch_bounds__(256, 4) void attn_kernel(
    const float* __restrict__ qkv, float* __restrict__ O) {
    __shared__ float lds[10432];
    float* Ks = lds;
    float* Vs = lds + 5216;
    const int t = threadIdx.x;
    const int qg = t & 3;
    const int chunk = t >> 2;              // 0..63
    const int head = blockIdx.y;
    const int qbase = blockIdx.x * 16 + qg * 4;
    const float SC = 0.25f * 1.4426950408889634f;   // log2e / sqrt(dh)

    float4 q[4][4];
    #pragma unroll
    for (int i = 0; i < 4; ++i) {
        if (qbase + i < SEQ) {
            const float4* qp = (const float4*)&qkv[(size_t)(qbase + i) * 384 + head * 16];
            #pragma unroll
            for (int j = 0; j < 4; ++j) {
                float4 v = qp[j];
                v.x *= SC; v.y *= SC; v.z *= SC; v.w *= SC;
                q[i][j] = v;
            }
        } else {
            #pragma unroll
            for (int j = 0; j < 4; ++j) q[i][j] = make_float4(0.f, 0.f, 0.f, 0.f);
        }
    }
    float m[4] = {-INFINITY, -INFINITY, -INFINITY, -INFINITY};
    float l[4] = {0.f, 0.f, 0.f, 0.f};
    float4 acc[4][4];
    #pragma unroll
    for (int i = 0; i < 4; ++i)
        #pragma unroll
        for (int j = 0; j < 4; ++j) acc[i][j] = make_float4(0.f, 0.f, 0.f, 0.f);

    for (int tile0 = 0; tile0 < SEQ; tile0 += 256) {
        if (tile0) __syncthreads();
        int j = tile0 + t;
        if (j < SEQ) {
            const float4* kp = (const float4*)&qkv[(size_t)j * 384 + 128 + head * 16];
            const float4* vp = (const float4*)&qkv[(size_t)j * 384 + 256 + head * 16];
            float4* kd = (float4*)&Ks[kvswz(t)];
            float4* vd = (float4*)&Vs[kvswz(t)];
            kd[0] = kp[0]; kd[1] = kp[1]; kd[2] = kp[2]; kd[3] = kp[3];
            vd[0] = vp[0]; vd[1] = vp[1]; vd[2] = vp[2]; vd[3] = vp[3];
        }
        __syncthreads();
        int cnt = SEQ - tile0; if (cnt > 256) cnt = 256;
        const int base = chunk * 4;
        if (base < cnt) {   // SEQ % 4 == 0 -> full groups of 4 always
            float s[4][4];   // [key][query]
            #pragma unroll
            for (int kx = 0; kx < 4; ++kx) {
                const float4* kr = (const float4*)&Ks[kvswz(base + kx)];
                float4 k0 = kr[0], k1 = kr[1], k2 = kr[2], k3 = kr[3];
                #pragma unroll
                for (int qi = 0; qi < 4; ++qi) {
                    float d = q[qi][0].x * k0.x + q[qi][0].y * k0.y + q[qi][0].z * k0.z + q[qi][0].w * k0.w;
                    d += q[qi][1].x * k1.x + q[qi][1].y * k1.y + q[qi][1].z * k1.z + q[qi][1].w * k1.w;
                    d += q[qi][2].x * k2.x + q[qi][2].y * k2.y + q[qi][2].z * k2.z + q[qi][2].w * k2.w;
                    d += q[qi][3].x * k3.x + q[qi][3].y * k3.y + q[qi][3].z * k3.z + q[qi][3].w * k3.w;
                    s[kx][qi] = d;
                }
            }
            float e[4][4];
            #pragma unroll
            for (int qi = 0; qi < 4; ++qi) {
                float gm = fmaxf(fmaxf(s[0][qi], s[1][qi]), fmaxf(s[2][qi], s[3][qi]));
                float nm = fmaxf(m[qi], gm);
                float corr = fexp2(m[qi] - nm);
                float e0 = fexp2(s[0][qi] - nm), e1 = fexp2(s[1][qi] - nm);
                float e2 = fexp2(s[2][qi] - nm), e3 = fexp2(s[3][qi] - nm);
                e[0][qi] = e0; e[1][qi] = e1; e[2][qi] = e2; e[3][qi] = e3;
                l[qi] = fmaf(l[qi], corr, (e0 + e1) + (e2 + e3));
                m[qi] = nm;
                #pragma unroll
                for (int j2 = 0; j2 < 4; ++j2) {
                    acc[qi][j2].x *= corr; acc[qi][j2].y *= corr;
                    acc[qi][j2].z *= corr; acc[qi][j2].w *= corr;
                }
            }
            #pragma unroll
            for (int kx = 0; kx < 4; ++kx) {
                const float4* vr = (const float4*)&Vs[kvswz(base + kx)];
                float4 v0 = vr[0], v1 = vr[1], v2 = vr[2], v3 = vr[3];
                #pragma unroll
                for (int qi = 0; qi < 4; ++qi) {
                    float ee = e[kx][qi];
                    acc[qi][0].x = fmaf(ee, v0.x, acc[qi][0].x);
                    acc[qi][0].y = fmaf(ee, v0.y, acc[qi][0].y);
                    acc[qi][0].z = fmaf(ee, v0.z, acc[qi][0].z);
                    acc[qi][0].w = fmaf(ee, v0.w, acc[qi][0].w);
                    acc[qi][1].x = fmaf(ee, v1.x, acc[qi][1].x);
                    acc[qi][1].y = fmaf(ee, v1.y, acc[qi][1].y);
                    acc[qi][1].z = fmaf(ee, v1.z, acc[qi][1].z);
                    acc[qi][1].w = fmaf(ee, v1.w, acc[qi][1].w);
                    acc[qi][2].x = fmaf(ee, v2.x, acc[qi][2].x);
                    acc[qi][2].y = fmaf(ee, v2.y, acc[qi][2].y);
                    acc[qi][2].z = fmaf(ee, v2.z, acc[qi][2].z);
                    acc[qi][2].w = fmaf(ee, v2.w, acc[qi][2].w);
                    acc[qi][3].x = fmaf(ee, v3.x, acc[qi][3].x);
                    acc[qi][3].y = fmaf(ee, v3.y, acc[qi][3].y);
                    acc[qi][3].z = fmaf(ee, v3.z, acc[qi][3].z);
                    acc[qi][3].w = fmaf(ee, v3.w, acc[qi][3].w);
                }
            }
        }
    }
    __syncthreads();

    // merge 16 chunk-partials sharing qg within each wave (masks 4..32)
    #pragma unroll
    for (int mask = 4; mask <= 32; mask <<= 1) {
        #pragma unroll
        for (int qi = 0; qi < 4; ++qi) {
            float m2 = __shfl_xor(m[qi], mask);
            float l2 = __shfl_xor(l[qi], mask);
            float M = fmaxf(m[qi], m2);
            float c1 = fexp2(m[qi] - M), c2 = fexp2(m2 - M);
            l[qi] = l[qi] * c1 + l2 * c2;
            #pragma unroll
            for (int j2 = 0; j2 < 4; ++j2) {
                float4 o = acc[qi][j2];
                float4 o2;
                o2.x = __shfl_xor(o.x, mask);
                o2.y = __shfl_xor(o.y, mask);
                o2.z = __shfl_xor(o.z, mask);
                o2.w = __shfl_xor(o.w, mask);
                o.x = o.x * c1 + o2.x * c2;
                o.y = o.y * c1 + o2.y * c2;
                o.z = o.z * c1 + o2.z * c2;
                o.w = o.w * c1 + o2.w * c2;
                acc[qi][j2] = o;
            }
            m[qi] = M;
        }
    }
    // 4 wave-partials per (qg,qi): 4 waves * 4 qg * 4 qi = 64 slots
    float* pacc = lds;            // 64*16 = 1024
    float* pm   = lds + 1024;     // 64
    float* pl   = lds + 1088;     // 64
    const int wv = t >> 6;
    if ((t & 63) < 4) {
        #pragma unroll
        for (int qi = 0; qi < 4; ++qi) {
            int slot = (wv * 4 + qg) * 4 + qi;
            float4* dst = (float4*)&pacc[slot * 16];
            dst[0] = acc[qi][0]; dst[1] = acc[qi][1];
            dst[2] = acc[qi][2]; dst[3] = acc[qi][3];
            pm[slot] = m[qi]; pl[slot] = l[qi];
        }
    }
    __syncthreads();
    if (t < 64) {
        const int row = t >> 2;           // 0..15
        const int part = t & 3;
        const int qrow = blockIdx.x * 16 + row;
        if (qrow < SEQ) {
            const int qg2 = row >> 2, qi2 = row & 3;
            float M = -INFINITY;
            #pragma unroll
            for (int w = 0; w < 4; ++w)
                M = fmaxf(M, pm[(w * 4 + qg2) * 4 + qi2]);
            float L = 0.f;
            float4 o = make_float4(0.f, 0.f, 0.f, 0.f);
            #pragma unroll
            for (int w = 0; w < 4; ++w) {
                int slot = (w * 4 + qg2) * 4 + qi2;
                float wgt = fexp2(pm[slot] - M);
                L = fmaf(pl[slot], wgt, L);
                float4 pa = ((const float4*)&pacc[slot * 16])[part];
                o.x = fmaf(pa.x, wgt, o.x); o.y = fmaf(pa.y, wgt, o.y);
                o.z = fmaf(pa.z, wgt, o.z); o.w = fmaf(pa.w, wgt, o.w);
            }
            float inv = 1.f / L;
            o.x *= inv; o.y *= inv; o.z *= inv; o.w *= inv;
            ((float4*)&O[(size_t)qrow * 128 + head * 16])[part] = o;
        }
    }
}

// ---- mega tail: region + map_fuse + channel-LN + conv1..4 + sigmoid-pool -------
// One block per image (100 blocks, 256 thr). Everything stays in LDS (~107 KB).
__global__ __launch_bounds__(256, 1) void tail_kernel(
    const float* __restrict__ sup, const float* __restrict__ qry,
    const float* __restrict__ X,
    const float* __restrict__ rg, const float* __restrict__ rb,
    const float* __restrict__ w1, const float* __restrict__ w2,
    const float* __restrict__ w3, const float* __restrict__ w4,
    float* __restrict__ out) {
    __shared__ float fused[12800];
    __shared__ float bufA[4608];   // key0 staging -> conv1 out -> sigmoid(conv4) flat
    __shared__ float bufB[4608];   // conv2 out (padded)
    __shared__ float bufC[4608];   // conv1 input chunks -> conv3 out (padded)
    __shared__ float meanF[100], rstdF[100], rfac[100];
    const int b = blockIdx.x;
    const int t = threadIdx.x;
    const float* feat = (b < 25) ? (sup + (size_t)b * 12800) : (qry + (size_t)(b - 25) * 12800);

    for (int i = t; i < 2048; i += 256) bufA[i] = X[i];   // key0 = X[0:16,:]
    __syncthreads();
    if (t < 100) {
        float dots[16];
        #pragma unroll
        for (int mm = 0; mm < 16; ++mm) dots[mm] = 0.f;
        float s = 0.f, ss = 0.f;
        for (int c = 0; c < 128; ++c) {
            float f = feat[c * 100 + t];
            s += f; ss += f * f;
            #pragma unroll
            for (int mm = 0; mm < 16; ++mm) dots[mm] += f * bufA[mm * 128 + c];
        }
        float mean16 = 0.f;
        #pragma unroll
        for (int mm = 0; mm < 16; ++mm) mean16 += 1.f / (1.f + expf(-dots[mm] * (1.f / 128.f)));
        float r = mean16 * (1.f / 16.f) + 1.f;
        rfac[t] = r;
        float mr = s * (1.f / 128.f);
        float vr = ss * (1.f / 128.f) - mr * mr;
        meanF[t] = mr * r;
        rstdF[t] = rsqrtf(vr * r * r + 1e-6f);
    }
    __syncthreads();
    for (int i = t; i < 12800; i += 256) fused[i] = feat[i] * rfac[i % 100];
    for (int i = t; i < 4608; i += 256) { bufA[i] = 0.f; bufB[i] = 0.f; }

    const int h = __builtin_amdgcn_readfirstlane(t >> 7);   // 0/1, wave-uniform
    const int p = t & 127;
    const int py = p / 10, px = p - py * 10;
    const bool active = p < 100;

    // conv1: LN(fused) -> bufA (relu, padded). 16 to-channels per thread.
    float acc1[16];
    #pragma unroll
    for (int j = 0; j < 16; ++j) acc1[j] = 0.f;
    for (int cb = 0; cb < 128; cb += 32) {
        __syncthreads();   // bufC free / fused+stats ready
        for (int i = t; i < 4608; i += 256) {
            int c = i / 144, pos = i - c * 144;
            int y = pos / 12 - 1, x = pos % 12 - 1;
            float v = 0.f;
            if ((unsigned)y < 10u && (unsigned)x < 10u) {
                int pp = y * 10 + x;
                v = (fused[(cb + c) * 100 + pp] - meanF[pp]) * rstdF[pp] * rg[cb + c] + rb[cb + c];
            }
            bufC[i] = v;
        }
        __syncthreads();
        if (active) {
            for (int c = 0; c < 32; ++c) {
                const float* sp = &bufC[c * 144 + py * 12 + px];
                float pix[9];
                #pragma unroll
                for (int k = 0; k < 9; ++k) pix[k] = sp[(k / 3) * 12 + (k % 3)];
                #pragma unroll
                for (int j = 0; j < 16; ++j) {
                    const float* wq = w1 + ((size_t)(h * 16 + j) * 128 + cb + c) * 9;
                    #pragma unroll
                    for (int k = 0; k < 9; ++k) acc1[j] = fmaf(pix[k], wq[k], acc1[j]);
                }
            }
        }
    }
    if (active) {
        #pragma unroll
        for (int j = 0; j < 16; ++j)
            bufA[(h * 16 + j) * 144 + (py + 1) * 12 + (px + 1)] = fmaxf(acc1[j], 0.f);
    }
    __syncthreads();

    // conv2: bufA -> bufB (relu); also zero bufC for conv3 output padding
    {
        for (int i = t; i < 4608; i += 256) bufC[i] = 0.f;
        float a2[16];
        #pragma unroll
        for (int j = 0; j < 16; ++j) a2[j] = 0.f;
        if (active) {
            for (int c = 0; c < 32; ++c) {
                const float* sp = &bufA[c * 144 + py * 12 + px];
                float pix[9];
                #pragma unroll
                for (int k = 0; k < 9; ++k) pix[k] = sp[(k / 3) * 12 + (k % 3)];
                #pragma unroll
                for (int j = 0; j < 16; ++j) {
                    const float* wq = w2 + ((size_t)(h * 16 + j) * 32 + c) * 9;
                    #pragma unroll
                    for (int k = 0; k < 9; ++k) a2[j] = fmaf(pix[k], wq[k], a2[j]);
                }
            }
        }
        __syncthreads();
        if (active) {
            #pragma unroll
            for (int j = 0; j < 16; ++j)
                bufB[(h * 16 + j) * 144 + (py + 1) * 12 + (px + 1)] = fmaxf(a2[j], 0.f);
        }
    }
    __syncthreads();

    // conv3: bufB -> bufC (relu)
    {
        float a3[16];
        #pragma unroll
        for (int j = 0; j < 16; ++j) a3[j] = 0.f;
        if (active) {
            for (int c = 0; c < 32; ++c) {
                const float* sp = &bufB[c * 144 + py * 12 + px];
                float pix[9];
                #pragma unroll
                for (int k = 0; k < 9; ++k) pix[k] = sp[(k / 3) * 12 + (k % 3)];
                #pragma unroll
                for (int j = 0; j < 16; ++j) {
                    const float* wq = w3 + ((size_t)(h * 16 + j) * 32 + c) * 9;
                    #pragma unroll
                    for (int k = 0; k < 9; ++k) a3[j] = fmaf(pix[k], wq[k], a3[j]);
                }
            }
            #pragma unroll
            for (int j = 0; j < 16; ++j)
                bufC[(h * 16 + j) * 144 + (py + 1) * 12 + (px + 1)] = fmaxf(a3[j], 0.f);
        }
    }
    __syncthreads();

    // conv4: bufC -> sigmoid -> bufA flat [to*100 + p]
    {
        float a4[16];
        #pragma unroll
        for (int j = 0; j < 16; ++j) a4[j] = 0.f;
        if (active) {
            for (int c = 0; c < 32; ++c) {
                const float* sp = &bufC[c * 144 + py * 12 + px];
                float pix[9];
                #pragma unroll
                for (int k = 0; k < 9; ++k) pix[k] = sp[(k / 3) * 12 + (k % 3)];
                #pragma unroll
                for (int j = 0; j < 16; ++j) {
                    const float* wq = w4 + ((size_t)(h * 16 + j) * 32 + c) * 9;
                    #pragma unroll
                    for (int k = 0; k < 9; ++k) a4[j] = fmaf(pix[k], wq[k], a4[j]);
                }
            }
        }
        __syncthreads();   // bufA (conv1 out) fully consumed by conv2
        if (active) {
            #pragma unroll
            for (int j = 0; j < 16; ++j)
                bufA[(h * 16 + j) * 100 + p] = 1.f / (1.f + expf(-a4[j]));
        }
    }
    __syncthreads();

    // pooling: out[b, c, tt] = (1/100) sum_p sig[tt][p] * fused[c][p]
    {
        const int tt = t & 31;
        const int cbase = t >> 5;          // c = cbase + 8k
        float accs[16];
        #pragma unroll
        for (int k = 0; k < 16; ++k) accs[k] = 0.f;
        for (int p0 = 0; p0 < 100; p0 += 4) {
            float4 s4 = *(const float4*)&bufA[tt * 100 + p0];
            #pragma unroll
            for (int k = 0; k < 16; ++k) {
                float4 f4 = *(const float4*)&fused[(cbase + 8 * k) * 100 + p0];
                accs[k] += s4.x * f4.x + s4.y * f4.y + s4.z * f4.z + s4.w * f4.w;
            }
        }
        #pragma unroll
        for (int k = 0; k < 16; ++k)
            out[(size_t)b * 4096 + (cbase + 8 * k) * 32 + tt] = accs[k] * 0.01f;
    }
}

extern "C" void kernel_launch(void* const* d_in, const int* in_sizes, int n_in,
                              void* d_out, int out_size, void* d_ws, size_t ws_size,
                              hipStream_t stream) {
    (void)in_sizes; (void)n_in; (void)out_size; (void)ws_size;
    const float* sup    = (const float*)d_in[0];
    const float* qry    = (const float*)d_in[1];
    const float* td     = (const float*)d_in[2];
    const float* ln1_g  = (const float*)d_in[3];
    const float* ln1_b  = (const float*)d_in[4];
    const float* qkv_w  = (const float*)d_in[5];
    const float* qkv_b  = (const float*)d_in[6];
    const float* out_w  = (const float*)d_in[7];
    const float* out_b  = (const float*)d_in[8];
    const float* ln2_g  = (const float*)d_in[9];
    const float* ln2_b  = (const float*)d_in[10];
    const float* mlp_w1 = (const float*)d_in[11];
    const float* mlp_b1 = (const float*)d_in[12];
    const float* mlp_w2 = (const float*)d_in[13];
    const float* mlp_b2 = (const float*)d_in[14];
    const float* rg     = (const float*)d_in[15];
    const float* rb     = (const float*)d_in[16];
    const float* c1     = (const float*)d_in[17];
    const float* c2     = (const float*)d_in[18];
    const float* c3     = (const float*)d_in[19];
    const float* c4     = (const float*)d_in[20];
    float* out = (float*)d_out;

    // buffers padded to 2520 rows for unguarded 8-row GEMM blocks
    float* ws   = (float*)d_ws;
    float* X    = ws;                  // 322560
    float* H    = X + 322560;          // 322560
    float* QKV  = H + 322560;          // 967680
    float* Obuf = QKV + 967680;        // 322560
    float* MLPH = Obuf + 322560;       // 1290240

    const int SG = (SEQ + 7) / 8;      // 315 blocks

    concat_ln_kernel<<<SEQ, 64, 0, stream>>>(td, sup, ln1_g, ln1_b, X, H);
    for (int i = 0; i < 2; ++i) {
        sgemm_kernel<384, 8, 0, false><<<SG, 384, 0, stream>>>(
            H, qkv_w + (size_t)i * 128 * 384, qkv_b + i * 384, nullptr, QKV, SEQ, 128);
        attn_kernel<<<dim3((SEQ + 15) / 16, 8), 256, 0, stream>>>(QKV, Obuf);
        // proj + residual -> X, then LN2 -> H
        sgemm_ln_kernel<<<SG, 512, 0, stream>>>(
            Obuf, out_w + (size_t)i * 128 * 128, out_b + i * 128, X, X, H,
            ln2_g + i * 128, ln2_b + i * 128, SEQ, 128);
        sgemm_kernel<512, 8, 1, false><<<SG, 512, 0, stream>>>(
            H, mlp_w1 + (size_t)i * 128 * 512, mlp_b1 + i * 512, nullptr, MLPH, SEQ, 128);
        // mlp2 + residual -> X, then LN1(next layer) -> H (unused garbage after layer 1)
        const float* ng = (i == 0) ? ln1_g + 128 : ln1_g;
        const float* nb = (i == 0) ? ln1_b + 128 : ln1_b;
        sgemm_ln_kernel<<<SG, 512, 0, stream>>>(
            MLPH, mlp_w2 + (size_t)i * 512 * 128, mlp_b2 + i * 128, X, X, H,
            ng, nb, SEQ, 512);
    }
    tail_kernel<<<100, 256, 0, stream>>>(sup, qry, X, rg, rb, c1, c2, c3, c4, out);
}

// Round 7
// 604.903 us; speedup vs baseline: 1.3542x; 1.3542x over previous
//
#include <hip/hip_runtime.h>
#include <math.h>

#define SEQ 2516
#define CDIM 128

__device__ __forceinline__ float gelu_exact(float x) {
    return x * 0.5f * (1.0f + erff(x * 0.7071067811865475f));
}
__device__ __forceinline__ float fexp2(float x) { return __builtin_amdgcn_exp2f(x); }

// ---------------- concat + LN1(layer0): one wave per row ------------------------
__global__ __launch_bounds__(64) void concat_ln_kernel(
    const float* __restrict__ td, const float* __restrict__ sup,
    const float* __restrict__ g, const float* __restrict__ b,
    float* __restrict__ X, float* __restrict__ H) {
    const int row = blockIdx.x;
    const int t = threadIdx.x;
    float x0, x1;
    if (row < 16) {
        x0 = td[row * 128 + t];
        x1 = td[row * 128 + 64 + t];
    } else {
        int r = row - 16;
        int n = r / 100, p = r - n * 100;
        x0 = sup[n * 12800 + t * 100 + p];
        x1 = sup[n * 12800 + (t + 64) * 100 + p];
    }
    X[row * 128 + t] = x0;
    X[row * 128 + 64 + t] = x1;
    float s = x0 + x1;
    for (int off = 32; off > 0; off >>= 1) s += __shfl_down(s, off);
    float mean = __shfl(s, 0) * (1.f / 128.f);
    float d0 = x0 - mean, d1 = x1 - mean;
    float v = d0 * d0 + d1 * d1;
    for (int off = 32; off > 0; off >>= 1) v += __shfl_down(v, off);
    float var = __shfl(v, 0) * (1.f / 128.f);
    float rstd = rsqrtf(var + 1e-5f);
    H[row * 128 + t]      = d0 * rstd * g[t] + b[t];
    H[row * 128 + 64 + t] = d1 * rstd * g[t + 64] + b[t + 64];
}

// ---------------- skinny GEMM: 8 M-rows x N cols per block ----------------------
template<int N, int RPT, int ACT, bool RES>
__global__ __launch_bounds__(N * 8 / RPT) void sgemm_kernel(
    const float* __restrict__ A, const float* __restrict__ W,
    const float* __restrict__ bias, const float* __restrict__ R,
    float* __restrict__ C, int M, int K) {
    const int t = threadIdx.x;
    const int c = t % N;
    const int grp = __builtin_amdgcn_readfirstlane(t / N);
    const int r0 = blockIdx.x * 8 + grp * RPT;
    float acc[RPT];
    #pragma unroll
    for (int i = 0; i < RPT; ++i) acc[i] = 0.f;
    #pragma unroll 4
    for (int k0 = 0; k0 < K; k0 += 4) {
        float w0 = W[(size_t)(k0 + 0) * N + c];
        float w1 = W[(size_t)(k0 + 1) * N + c];
        float w2 = W[(size_t)(k0 + 2) * N + c];
        float w3 = W[(size_t)(k0 + 3) * N + c];
        #pragma unroll
        for (int i = 0; i < RPT; ++i) {
            float4 a4 = *(const float4*)&A[(size_t)(r0 + i) * K + k0];
            acc[i] = fmaf(a4.x, w0, acc[i]);
            acc[i] = fmaf(a4.y, w1, acc[i]);
            acc[i] = fmaf(a4.z, w2, acc[i]);
            acc[i] = fmaf(a4.w, w3, acc[i]);
        }
    }
    float bv = bias[c];
    #pragma unroll
    for (int i = 0; i < RPT; ++i) {
        int row = r0 + i;
        if (row < M) {
            float v = acc[i] + bv;
            if (ACT == 1) v = gelu_exact(v);
            if (RES) v += R[(size_t)row * N + c];
            C[(size_t)row * N + c] = v;
        }
    }
}

// ------- skinny GEMM N=128 + residual + row-LN epilogue (writes C and H) --------
__global__ __launch_bounds__(512) void sgemm_ln_kernel(
    const float* __restrict__ A, const float* __restrict__ W,
    const float* __restrict__ bias, const float* __restrict__ R,
    float* __restrict__ C, float* __restrict__ H,
    const float* __restrict__ g, const float* __restrict__ bb, int M, int K) {
    __shared__ float ln[8][130];
    const int t = threadIdx.x;
    const int c = t & 127;
    const int grp = __builtin_amdgcn_readfirstlane(t >> 7);
    const int r0 = blockIdx.x * 8 + grp * 2;
    float acc0 = 0.f, acc1 = 0.f;
    #pragma unroll 4
    for (int k0 = 0; k0 < K; k0 += 4) {
        float w0 = W[(size_t)(k0 + 0) * 128 + c];
        float w1 = W[(size_t)(k0 + 1) * 128 + c];
        float w2 = W[(size_t)(k0 + 2) * 128 + c];
        float w3 = W[(size_t)(k0 + 3) * 128 + c];
        float4 a0 = *(const float4*)&A[(size_t)(r0 + 0) * K + k0];
        float4 a1 = *(const float4*)&A[(size_t)(r0 + 1) * K + k0];
        acc0 = fmaf(a0.x, w0, acc0); acc0 = fmaf(a0.y, w1, acc0);
        acc0 = fmaf(a0.z, w2, acc0); acc0 = fmaf(a0.w, w3, acc0);
        acc1 = fmaf(a1.x, w0, acc1); acc1 = fmaf(a1.y, w1, acc1);
        acc1 = fmaf(a1.z, w2, acc1); acc1 = fmaf(a1.w, w3, acc1);
    }
    float bv = bias[c];
    float v0 = acc0 + bv + R[(size_t)(r0 + 0) * 128 + c];
    float v1 = acc1 + bv + R[(size_t)(r0 + 1) * 128 + c];
    ln[grp * 2 + 0][c] = v0;
    ln[grp * 2 + 1][c] = v1;
    if (r0 + 0 < M) C[(size_t)(r0 + 0) * 128 + c] = v0;
    if (r0 + 1 < M) C[(size_t)(r0 + 1) * 128 + c] = v1;
    __syncthreads();
    const int wv = t >> 6, l = t & 63;
    float x0 = ln[wv][l], x1 = ln[wv][l + 64];
    float s = x0 + x1;
    for (int off = 32; off > 0; off >>= 1) s += __shfl_down(s, off);
    float mean = __shfl(s, 0) * (1.f / 128.f);
    float d0 = x0 - mean, d1 = x1 - mean;
    float vv = d0 * d0 + d1 * d1;
    for (int off = 32; off > 0; off >>= 1) vv += __shfl_down(vv, off);
    float var = __shfl(vv, 0) * (1.f / 128.f);
    float rstd = rsqrtf(var + 1e-5f);
    const int hrow = blockIdx.x * 8 + wv;
    H[(size_t)hrow * 128 + l]      = d0 * rstd * g[l] + bb[l];
    H[(size_t)hrow * 128 + 64 + l] = d1 * rstd * g[l + 64] + bb[l + 64];
}

// ---------------- attention v6: fp32, QB=4, Q-tile 16, swizzled LDS -------------
__device__ __forceinline__ int kvswz(int r) { return r * 20 + ((r >> 4) & 3) * 8; }

__global__ __launch_bounds__(256, 4) void attn_kernel(
    const float* __restrict__ qkv, float* __restrict__ O) {
    __shared__ float lds[10432];
    float* Ks = lds;
    float* Vs = lds + 5216;
    const int t = threadIdx.x;
    const int qg = t & 3;
    const int chunk = t >> 2;              // 0..63
    const int head = blockIdx.y;
    const int qbase = blockIdx.x * 16 + qg * 4;
    const float SC = 0.25f * 1.4426950408889634f;   // log2e / sqrt(dh)

    float4 q[4][4];
    #pragma unroll
    for (int i = 0; i < 4; ++i) {
        if (qbase + i < SEQ) {
            const float4* qp = (const float4*)&qkv[(size_t)(qbase + i) * 384 + head * 16];
            #pragma unroll
            for (int j = 0; j < 4; ++j) {
                float4 v = qp[j];
                v.x *= SC; v.y *= SC; v.z *= SC; v.w *= SC;
                q[i][j] = v;
            }
        } else {
            #pragma unroll
            for (int j = 0; j < 4; ++j) q[i][j] = make_float4(0.f, 0.f, 0.f, 0.f);
        }
    }
    float m[4] = {-INFINITY, -INFINITY, -INFINITY, -INFINITY};
    float l[4] = {0.f, 0.f, 0.f, 0.f};
    float4 acc[4][4];
    #pragma unroll
    for (int i = 0; i < 4; ++i)
        #pragma unroll
        for (int j = 0; j < 4; ++j) acc[i][j] = make_float4(0.f, 0.f, 0.f, 0.f);

    for (int tile0 = 0; tile0 < SEQ; tile0 += 256) {
        if (tile0) __syncthreads();
        int j = tile0 + t;
        if (j < SEQ) {
            const float4* kp = (const float4*)&qkv[(size_t)j * 384 + 128 + head * 16];
            const float4* vp = (const float4*)&qkv[(size_t)j * 384 + 256 + head * 16];
            float4* kd = (float4*)&Ks[kvswz(t)];
            float4* vd = (float4*)&Vs[kvswz(t)];
            kd[0] = kp[0]; kd[1] = kp[1]; kd[2] = kp[2]; kd[3] = kp[3];
            vd[0] = vp[0]; vd[1] = vp[1]; vd[2] = vp[2]; vd[3] = vp[3];
        }
        __syncthreads();
        int cnt = SEQ - tile0; if (cnt > 256) cnt = 256;
        const int base = chunk * 4;
        if (base < cnt) {   // SEQ % 4 == 0 -> full groups of 4 always
            float s[4][4];   // [key][query]
            #pragma unroll
            for (int kx = 0; kx < 4; ++kx) {
                const float4* kr = (const float4*)&Ks[kvswz(base + kx)];
                float4 k0 = kr[0], k1 = kr[1], k2 = kr[2], k3 = kr[3];
                #pragma unroll
                for (int qi = 0; qi < 4; ++qi) {
                    float d = q[qi][0].x * k0.x + q[qi][0].y * k0.y + q[qi][0].z * k0.z + q[qi][0].w * k0.w;
                    d += q[qi][1].x * k1.x + q[qi][1].y * k1.y + q[qi][1].z * k1.z + q[qi][1].w * k1.w;
                    d += q[qi][2].x * k2.x + q[qi][2].y * k2.y + q[qi][2].z * k2.z + q[qi][2].w * k2.w;
                    d += q[qi][3].x * k3.x + q[qi][3].y * k3.y + q[qi][3].z * k3.z + q[qi][3].w * k3.w;
                    s[kx][qi] = d;
                }
            }
            float e[4][4];
            #pragma unroll
            for (int qi = 0; qi < 4; ++qi) {
                float gm = fmaxf(fmaxf(s[0][qi], s[1][qi]), fmaxf(s[2][qi], s[3][qi]));
                float nm = fmaxf(m[qi], gm);
                float corr = fexp2(m[qi] - nm);
                float e0 = fexp2(s[0][qi] - nm), e1 = fexp2(s[1][qi] - nm);
                float e2 = fexp2(s[2][qi] - nm), e3 = fexp2(s[3][qi] - nm);
                e[0][qi] = e0; e[1][qi] = e1; e[2][qi] = e2; e[3][qi] = e3;
                l[qi] = fmaf(l[qi], corr, (e0 + e1) + (e2 + e3));
                m[qi] = nm;
                #pragma unroll
                for (int j2 = 0; j2 < 4; ++j2) {
                    acc[qi][j2].x *= corr; acc[qi][j2].y *= corr;
                    acc[qi][j2].z *= corr; acc[qi][j2].w *= corr;
                }
            }
            #pragma unroll
            for (int kx = 0; kx < 4; ++kx) {
                const float4* vr = (const float4*)&Vs[kvswz(base + kx)];
                float4 v0 = vr[0], v1 = vr[1], v2 = vr[2], v3 = vr[3];
                #pragma unroll
                for (int qi = 0; qi < 4; ++qi) {
                    float ee = e[kx][qi];
                    acc[qi][0].x = fmaf(ee, v0.x, acc[qi][0].x);
                    acc[qi][0].y = fmaf(ee, v0.y, acc[qi][0].y);
                    acc[qi][0].z = fmaf(ee, v0.z, acc[qi][0].z);
                    acc[qi][0].w = fmaf(ee, v0.w, acc[qi][0].w);
                    acc[qi][1].x = fmaf(ee, v1.x, acc[qi][1].x);
                    acc[qi][1].y = fmaf(ee, v1.y, acc[qi][1].y);
                    acc[qi][1].z = fmaf(ee, v1.z, acc[qi][1].z);
                    acc[qi][1].w = fmaf(ee, v1.w, acc[qi][1].w);
                    acc[qi][2].x = fmaf(ee, v2.x, acc[qi][2].x);
                    acc[qi][2].y = fmaf(ee, v2.y, acc[qi][2].y);
                    acc[qi][2].z = fmaf(ee, v2.z, acc[qi][2].z);
                    acc[qi][2].w = fmaf(ee, v2.w, acc[qi][2].w);
                    acc[qi][3].x = fmaf(ee, v3.x, acc[qi][3].x);
                    acc[qi][3].y = fmaf(ee, v3.y, acc[qi][3].y);
                    acc[qi][3].z = fmaf(ee, v3.z, acc[qi][3].z);
                    acc[qi][3].w = fmaf(ee, v3.w, acc[qi][3].w);
                }
            }
        }
    }
    __syncthreads();

    #pragma unroll
    for (int mask = 4; mask <= 32; mask <<= 1) {
        #pragma unroll
        for (int qi = 0; qi < 4; ++qi) {
            float m2 = __shfl_xor(m[qi], mask);
            float l2 = __shfl_xor(l[qi], mask);
            float M = fmaxf(m[qi], m2);
            float c1 = fexp2(m[qi] - M), c2 = fexp2(m2 - M);
            l[qi] = l[qi] * c1 + l2 * c2;
            #pragma unroll
            for (int j2 = 0; j2 < 4; ++j2) {
                float4 o = acc[qi][j2];
                float4 o2;
                o2.x = __shfl_xor(o.x, mask);
                o2.y = __shfl_xor(o.y, mask);
                o2.z = __shfl_xor(o.z, mask);
                o2.w = __shfl_xor(o.w, mask);
                o.x = o.x * c1 + o2.x * c2;
                o.y = o.y * c1 + o2.y * c2;
                o.z = o.z * c1 + o2.z * c2;
                o.w = o.w * c1 + o2.w * c2;
                acc[qi][j2] = o;
            }
            m[qi] = M;
        }
    }
    float* pacc = lds;            // 64*16 = 1024
    float* pm   = lds + 1024;     // 64
    float* pl   = lds + 1088;     // 64
    const int wv = t >> 6;
    if ((t & 63) < 4) {
        #pragma unroll
        for (int qi = 0; qi < 4; ++qi) {
            int slot = (wv * 4 + qg) * 4 + qi;
            float4* dst = (float4*)&pacc[slot * 16];
            dst[0] = acc[qi][0]; dst[1] = acc[qi][1];
            dst[2] = acc[qi][2]; dst[3] = acc[qi][3];
            pm[slot] = m[qi]; pl[slot] = l[qi];
        }
    }
    __syncthreads();
    if (t < 64) {
        const int row = t >> 2;           // 0..15
        const int part = t & 3;
        const int qrow = blockIdx.x * 16 + row;
        if (qrow < SEQ) {
            const int qg2 = row >> 2, qi2 = row & 3;
            float M = -INFINITY;
            #pragma unroll
            for (int w = 0; w < 4; ++w)
                M = fmaxf(M, pm[(w * 4 + qg2) * 4 + qi2]);
            float L = 0.f;
            float4 o = make_float4(0.f, 0.f, 0.f, 0.f);
            #pragma unroll
            for (int w = 0; w < 4; ++w) {
                int slot = (w * 4 + qg2) * 4 + qi2;
                float wgt = fexp2(pm[slot] - M);
                L = fmaf(pl[slot], wgt, L);
                float4 pa = ((const float4*)&pacc[slot * 16])[part];
                o.x = fmaf(pa.x, wgt, o.x); o.y = fmaf(pa.y, wgt, o.y);
                o.z = fmaf(pa.z, wgt, o.z); o.w = fmaf(pa.w, wgt, o.w);
            }
            float inv = 1.f / L;
            o.x *= inv; o.y *= inv; o.z *= inv; o.w *= inv;
            ((float4*)&O[(size_t)qrow * 128 + head * 16])[part] = o;
        }
    }
}

// ---- region + map_fuse + channel-LN stats (fused) ------------------------------
__global__ __launch_bounds__(256) void region_fuse_stats_kernel(
    const float* __restrict__ sup, const float* __restrict__ qry,
    const float* __restrict__ X, float* __restrict__ fused,
    float* __restrict__ MEAN, float* __restrict__ RSTD) {
    __shared__ float key0[2048];   // 16 x 128
    __shared__ float rfac[100];
    const int b = blockIdx.x;
    const int t = threadIdx.x;
    const float* feat = (b < 25) ? (sup + (size_t)b * 12800) : (qry + (size_t)(b - 25) * 12800);
    for (int i = t; i < 2048; i += 256) key0[i] = X[i];
    __syncthreads();
    if (t < 100) {
        float dots[16];
        #pragma unroll
        for (int mm = 0; mm < 16; ++mm) dots[mm] = 0.f;
        float s = 0.f, ss = 0.f;
        for (int c = 0; c < 128; ++c) {
            float f = feat[c * 100 + t];
            s += f; ss += f * f;
            #pragma unroll
            for (int mm = 0; mm < 16; ++mm) dots[mm] += f * key0[mm * 128 + c];
        }
        float mean16 = 0.f;
        #pragma unroll
        for (int mm = 0; mm < 16; ++mm) mean16 += 1.f / (1.f + expf(-dots[mm] * (1.f / 128.f)));
        float r = mean16 * (1.f / 16.f) + 1.f;
        rfac[t] = r;
        float mr = s * (1.f / 128.f);
        float vr = ss * (1.f / 128.f) - mr * mr;
        MEAN[b * 128 + t] = mr * r;
        RSTD[b * 128 + t] = rsqrtf(vr * r * r + 1e-6f);
    }
    __syncthreads();
    for (int i = t; i < 12800; i += 256)
        fused[(size_t)b * 12800 + i] = feat[i] * rfac[i % 100];
}

// ---------------- 3x3 conv, pad 1, 10x10 images --------------------------------
template<int CIN, bool RELU, bool FUSE_LN>
__global__ __launch_bounds__(256) void conv3x3_kernel(
    const float* __restrict__ in, const float* __restrict__ w,
    const float* __restrict__ MEAN, const float* __restrict__ RSTD,
    const float* __restrict__ g, const float* __restrict__ bb,
    float* __restrict__ out) {
    __shared__ float sin_[32 * 144];
    const int b = blockIdx.x;
    const int base_to = blockIdx.y * 8;
    const int t = threadIdx.x;
    const int h = __builtin_amdgcn_readfirstlane(t >> 7);   // wave-uniform
    const int p = t & 127;
    const int py = p / 10, px = p - py * 10;
    const bool active = p < 100;
    float acc[4] = {0.f, 0.f, 0.f, 0.f};
    for (int cb = 0; cb < CIN; cb += 32) {
        if (cb) __syncthreads();
        for (int i = t; i < 32 * 144; i += 256) {
            int c = i / 144, pos = i - c * 144;
            int y = pos / 12 - 1, x = pos % 12 - 1;
            float v = 0.f;
            if ((unsigned)y < 10u && (unsigned)x < 10u) {
                int pp = y * 10 + x;
                float raw = in[(size_t)b * CIN * 100 + (cb + c) * 100 + pp];
                if (FUSE_LN)
                    v = (raw - MEAN[b * 128 + pp]) * RSTD[b * 128 + pp] * g[cb + c] + bb[cb + c];
                else
                    v = raw;
            }
            sin_[i] = v;
        }
        __syncthreads();
        if (active) {
            const float* wbase = w + ((size_t)(base_to + h * 4) * CIN + cb) * 9;
            for (int c = 0; c < 32; ++c) {
                const float* sp = &sin_[c * 144 + py * 12 + px];
                float pix[9];
                #pragma unroll
                for (int k = 0; k < 9; ++k) pix[k] = sp[(k / 3) * 12 + (k % 3)];
                #pragma unroll
                for (int j = 0; j < 4; ++j) {
                    const float* wq = wbase + ((size_t)j * CIN + c) * 9;
                    #pragma unroll
                    for (int k = 0; k < 9; ++k) acc[j] = fmaf(pix[k], wq[k], acc[j]);
                }
            }
        }
    }
    if (active) {
        #pragma unroll
        for (int j = 0; j < 4; ++j) {
            float v = acc[j];
            if (RELU) v = fmaxf(v, 0.f);
            out[(size_t)b * 3200 + (base_to + h * 4 + j) * 100 + p] = v;
        }
    }
}

// ---------------- final pooling -------------------------------------------------
__global__ __launch_bounds__(256) void rfm_out_kernel(
    const float* __restrict__ conv4, const float* __restrict__ fused, float* __restrict__ out) {
    __shared__ float sig[3200];
    __shared__ float sf[12800];
    const int b = blockIdx.x;
    const int t = threadIdx.x;
    for (int i = t; i < 3200; i += 256) sig[i] = 1.f / (1.f + expf(-conv4[(size_t)b * 3200 + i]));
    for (int i = t; i < 12800; i += 256) sf[i] = fused[(size_t)b * 12800 + i];
    __syncthreads();
    for (int o = t; o < 4096; o += 256) {
        int c = o >> 5, tt = o & 31;
        float acc = 0.f;
        for (int p = 0; p < 100; ++p) acc += sig[tt * 100 + p] * sf[c * 100 + p];
        out[(size_t)b * 4096 + o] = acc * 0.01f;
    }
}

extern "C" void kernel_launch(void* const* d_in, const int* in_sizes, int n_in,
                              void* d_out, int out_size, void* d_ws, size_t ws_size,
                              hipStream_t stream) {
    (void)in_sizes; (void)n_in; (void)out_size; (void)ws_size;
    const float* sup    = (const float*)d_in[0];
    const float* qry    = (const float*)d_in[1];
    const float* td     = (const float*)d_in[2];
    const float* ln1_g  = (const float*)d_in[3];
    const float* ln1_b  = (const float*)d_in[4];
    const float* qkv_w  = (const float*)d_in[5];
    const float* qkv_b  = (const float*)d_in[6];
    const float* out_w  = (const float*)d_in[7];
    const float* out_b  = (const float*)d_in[8];
    const float* ln2_g  = (const float*)d_in[9];
    const float* ln2_b  = (const float*)d_in[10];
    const float* mlp_w1 = (const float*)d_in[11];
    const float* mlp_b1 = (const float*)d_in[12];
    const float* mlp_w2 = (const float*)d_in[13];
    const float* mlp_b2 = (const float*)d_in[14];
    const float* rg     = (const float*)d_in[15];
    const float* rb     = (const float*)d_in[16];
    const float* c1     = (const float*)d_in[17];
    const float* c2     = (const float*)d_in[18];
    const float* c3     = (const float*)d_in[19];
    const float* c4     = (const float*)d_in[20];
    float* out = (float*)d_out;

    // buffers padded to 2520 rows for unguarded 8-row GEMM blocks
    float* ws   = (float*)d_ws;
    float* X    = ws;                  // 322560
    float* H    = X + 322560;          // 322560
    float* QKV  = H + 322560;          // 967680
    float* Obuf = QKV + 967680;        // 322560
    float* MLPH = Obuf + 322560;       // 1290240
    float* FUSED= MLPH + 1290240;      // 1280000
    float* MEAN = FUSED + 1280000;     // 12800
    float* RSTD = MEAN + 12800;        // 12800
    float* CB1  = RSTD + 12800;        // 320000
    float* CB2  = CB1 + 320000;        // 320000

    const int SG = (SEQ + 7) / 8;      // 315 blocks

    concat_ln_kernel<<<SEQ, 64, 0, stream>>>(td, sup, ln1_g, ln1_b, X, H);
    for (int i = 0; i < 2; ++i) {
        sgemm_kernel<384, 8, 0, false><<<SG, 384, 0, stream>>>(
            H, qkv_w + (size_t)i * 128 * 384, qkv_b + i * 384, nullptr, QKV, SEQ, 128);
        attn_kernel<<<dim3((SEQ + 15) / 16, 8), 256, 0, stream>>>(QKV, Obuf);
        sgemm_ln_kernel<<<SG, 512, 0, stream>>>(
            Obuf, out_w + (size_t)i * 128 * 128, out_b + i * 128, X, X, H,
            ln2_g + i * 128, ln2_b + i * 128, SEQ, 128);
        sgemm_kernel<512, 8, 1, false><<<SG, 512, 0, stream>>>(
            H, mlp_w1 + (size_t)i * 128 * 512, mlp_b1 + i * 512, nullptr, MLPH, SEQ, 128);
        const float* ng = (i == 0) ? ln1_g + 128 : ln1_g;
        const float* nb = (i == 0) ? ln1_b + 128 : ln1_b;
        sgemm_ln_kernel<<<SG, 512, 0, stream>>>(
            MLPH, mlp_w2 + (size_t)i * 512 * 128, mlp_b2 + i * 128, X, X, H,
            ng, nb, SEQ, 512);
    }
    region_fuse_stats_kernel<<<100, 256, 0, stream>>>(sup, qry, X, FUSED, MEAN, RSTD);
    conv3x3_kernel<128, true,  true ><<<dim3(100, 4), 256, 0, stream>>>(FUSED, c1, MEAN, RSTD, rg, rb, CB1);
    conv3x3_kernel< 32, true,  false><<<dim3(100, 4), 256, 0, stream>>>(CB1, c2, nullptr, nullptr, nullptr, nullptr, CB2);
    conv3x3_kernel< 32, true,  false><<<dim3(100, 4), 256, 0, stream>>>(CB2, c3, nullptr, nullptr, nullptr, nullptr, CB1);
    conv3x3_kernel< 32, false, false><<<dim3(100, 4), 256, 0, stream>>>(CB1, c4, nullptr, nullptr, nullptr, nullptr, CB2);
    rfm_out_kernel<<<100, 256, 0, stream>>>(CB2, FUSED, out);
}